// Round 1
// baseline (221.760 us; speedup 1.0000x reference)
//
#include <hip/hip_runtime.h>

typedef __attribute__((ext_vector_type(8))) short bf16x8;
typedef __attribute__((ext_vector_type(8))) unsigned short u16x8;
typedef __attribute__((ext_vector_type(4))) float f32x4;

#define MFMA16 __builtin_amdgcn_mfma_f32_16x16x32_bf16

constexpr int Bc = 4, Lc = 2048, Hc = 16, Dc = 64;
// (1/sqrt(64)) * log2(e)
constexpr float SCL = 0.18033688011112042f;

__device__ __forceinline__ unsigned short f2bf(float f) {
  unsigned u = __float_as_uint(f);
  u += 0x7fff + ((u >> 16) & 1);   // RNE
  return (unsigned short)(u >> 16);
}

__device__ __forceinline__ float fexp2(float x) {
  return __builtin_amdgcn_exp2f(x);
}

__global__ __launch_bounds__(256)
void fattn_kernel(const float* __restrict__ Qg, const float* __restrict__ Kg,
                  const float* __restrict__ Vg, float* __restrict__ Og) {
  __shared__ __align__(128) char smem[32768];
  char* smK = smem;            // K tile [64 k][64 d] bf16, row-swizzled
  char* smV = smem + 16384;    // V^T tile [64 d][64 k] bf16, row-swizzled

  const int bid  = blockIdx.x;
  const int head = bid >> 5;       // 64 (b,h) pairs
  const int qt   = bid & 31;       // q-tile index
  const int b    = head >> 4;
  const int h    = head & 15;
  const int q0   = qt * 64;

  const int tid = threadIdx.x;
  const int w   = tid >> 6;        // wave 0..3
  const int l   = tid & 63;
  const int lo  = l & 15;
  const int hi4 = l >> 4;          // 0..3

  // ---- Q fragments (B-operand of S^T = K * Q^T), hoisted ----
  const int qrow = q0 + w * 16 + lo;
  const float* qp = Qg + ((size_t)((b * Lc + qrow) * Hc + h)) * Dc;
  bf16x8 qf[2];
#pragma unroll
  for (int dc = 0; dc < 2; ++dc) {
    float4 a = *reinterpret_cast<const float4*>(qp + dc * 32 + hi4 * 8);
    float4 c = *reinterpret_cast<const float4*>(qp + dc * 32 + hi4 * 8 + 4);
    bf16x8 f;
    f[0] = (short)f2bf(a.x); f[1] = (short)f2bf(a.y);
    f[2] = (short)f2bf(a.z); f[3] = (short)f2bf(a.w);
    f[4] = (short)f2bf(c.x); f[5] = (short)f2bf(c.y);
    f[6] = (short)f2bf(c.z); f[7] = (short)f2bf(c.w);
    qf[dc] = f;
  }

  f32x4 o[4];
#pragma unroll
  for (int dt = 0; dt < 4; ++dt) { o[dt][0] = 0.f; o[dt][1] = 0.f; o[dt][2] = 0.f; o[dt][3] = 0.f; }
  float m_run = -3.0e38f, l_run = 0.0f;

  // staging thread mapping: thread -> (row sk, 16-col segment sd)
  const int sk   = tid >> 2;
  const int sd   = (tid & 3) * 16;
  const int swzK = (sk & 7) << 4;
  const int swzA = (lo & 7) << 4;

  const int nkt = qt + 1;
  for (int kt = 0; kt < nkt; ++kt) {
    const int kv0 = kt * 64;
    __syncthreads();
    {
      // ---- stage K tile: natural [k][d], bf16, swizzled ----
      const float* kpr = Kg + ((size_t)((b * Lc + kv0 + sk) * Hc + h)) * Dc + sd;
      float4 c0 = *reinterpret_cast<const float4*>(kpr + 0);
      float4 c1 = *reinterpret_cast<const float4*>(kpr + 4);
      float4 c2 = *reinterpret_cast<const float4*>(kpr + 8);
      float4 c3 = *reinterpret_cast<const float4*>(kpr + 12);
      u16x8 w0, w1;
      w0[0] = f2bf(c0.x); w0[1] = f2bf(c0.y); w0[2] = f2bf(c0.z); w0[3] = f2bf(c0.w);
      w0[4] = f2bf(c1.x); w0[5] = f2bf(c1.y); w0[6] = f2bf(c1.z); w0[7] = f2bf(c1.w);
      w1[0] = f2bf(c2.x); w1[1] = f2bf(c2.y); w1[2] = f2bf(c2.z); w1[3] = f2bf(c2.w);
      w1[4] = f2bf(c3.x); w1[5] = f2bf(c3.y); w1[6] = f2bf(c3.z); w1[7] = f2bf(c3.w);
      *reinterpret_cast<u16x8*>(smK + sk * 128 + ((sd * 2) ^ swzK)) = w0;
      *reinterpret_cast<u16x8*>(smK + sk * 128 + ((sd * 2 + 16) ^ swzK)) = w1;

      // ---- stage V transposed: [d][k], bf16, swizzled ----
      const float* vpr = Vg + ((size_t)((b * Lc + kv0 + sk) * Hc + h)) * Dc + sd;
      float4 v0 = *reinterpret_cast<const float4*>(vpr + 0);
      float4 v1 = *reinterpret_cast<const float4*>(vpr + 4);
      float4 v2 = *reinterpret_cast<const float4*>(vpr + 8);
      float4 v3 = *reinterpret_cast<const float4*>(vpr + 12);
      float vv[16];
      vv[0] = v0.x; vv[1] = v0.y; vv[2] = v0.z; vv[3] = v0.w;
      vv[4] = v1.x; vv[5] = v1.y; vv[6] = v1.z; vv[7] = v1.w;
      vv[8] = v2.x; vv[9] = v2.y; vv[10] = v2.z; vv[11] = v2.w;
      vv[12] = v3.x; vv[13] = v3.y; vv[14] = v3.z; vv[15] = v3.w;
#pragma unroll
      for (int j = 0; j < 16; ++j) {
        const int d = sd + j;
        *reinterpret_cast<unsigned short*>(smV + d * 128 + ((sk * 2) ^ ((j & 7) << 4))) = f2bf(vv[j]);
      }
    }
    __syncthreads();

    // ---- S^T = K * Q^T : 4 k-subtiles of 16, K-dim = D = 2x32 ----
    f32x4 s[4];
#pragma unroll
    for (int ks = 0; ks < 4; ++ks) {
      const int rb = (ks * 16 + lo) * 128;
      bf16x8 a0 = *reinterpret_cast<const bf16x8*>(smK + rb + ((hi4 * 16) ^ swzA));
      bf16x8 a1 = *reinterpret_cast<const bf16x8*>(smK + rb + ((64 + hi4 * 16) ^ swzA));
      f32x4 c; c[0] = 0.f; c[1] = 0.f; c[2] = 0.f; c[3] = 0.f;
      c = MFMA16(a0, qf[0], c, 0, 0, 0);
      c = MFMA16(a1, qf[1], c, 0, 0, 0);
      s[ks] = c;
    }

    // ---- scale + causal mask + online softmax (lane holds 16 k for q=lo) ----
    const bool diag = (kt == nkt - 1);
    float vmax = -3.0e38f;
#pragma unroll
    for (int ks = 0; ks < 4; ++ks) {
#pragma unroll
      for (int i = 0; i < 4; ++i) {
        float x = s[ks][i] * SCL;
        if (diag) {
          const int kg = kv0 + ks * 16 + hi4 * 4 + i;
          if (kg > qrow) x = -3.0e38f;
        }
        s[ks][i] = x;
        vmax = fmaxf(vmax, x);
      }
    }
    vmax = fmaxf(vmax, __shfl_xor(vmax, 16));
    vmax = fmaxf(vmax, __shfl_xor(vmax, 32));
    const float m_new = fmaxf(m_run, vmax);
    const float alpha = fexp2(m_run - m_new);

    float rsum = 0.f;
    unsigned pk2[4][2];
#pragma unroll
    for (int ks = 0; ks < 4; ++ks) {
      const float p0 = fexp2(s[ks][0] - m_new);
      const float p1 = fexp2(s[ks][1] - m_new);
      const float p2 = fexp2(s[ks][2] - m_new);
      const float p3 = fexp2(s[ks][3] - m_new);
      rsum += (p0 + p1) + (p2 + p3);
      pk2[ks][0] = (unsigned)f2bf(p0) | ((unsigned)f2bf(p1) << 16);
      pk2[ks][1] = (unsigned)f2bf(p2) | ((unsigned)f2bf(p3) << 16);
    }
    rsum += __shfl_xor(rsum, 16);
    rsum += __shfl_xor(rsum, 32);
    l_run = l_run * alpha + rsum;
    m_run = m_new;
#pragma unroll
    for (int dt = 0; dt < 4; ++dt) {
      o[dt][0] *= alpha; o[dt][1] *= alpha; o[dt][2] *= alpha; o[dt][3] *= alpha;
    }

    // ---- rearrange P^T (C-layout) into K=32 B-fragments via 16 shfls ----
    const int srcA = lo + ((l & 16) << 1);   // lo + 32*(hi4&1)
    const int srcB = srcA + 16;
    const bool up = (l & 32) != 0;           // hi4 >= 2
    bf16x8 pf[2];
#pragma unroll
    for (int c2 = 0; c2 < 2; ++c2) {
      const unsigned A0x = (unsigned)__shfl((int)pk2[2 * c2][0], srcA);
      const unsigned A0y = (unsigned)__shfl((int)pk2[2 * c2][1], srcA);
      const unsigned A1x = (unsigned)__shfl((int)pk2[2 * c2][0], srcB);
      const unsigned A1y = (unsigned)__shfl((int)pk2[2 * c2][1], srcB);
      const unsigned B0x = (unsigned)__shfl((int)pk2[2 * c2 + 1][0], srcA);
      const unsigned B0y = (unsigned)__shfl((int)pk2[2 * c2 + 1][1], srcA);
      const unsigned B1x = (unsigned)__shfl((int)pk2[2 * c2 + 1][0], srcB);
      const unsigned B1y = (unsigned)__shfl((int)pk2[2 * c2 + 1][1], srcB);
      union { unsigned u[4]; bf16x8 v; } cvt;
      cvt.u[0] = up ? B0x : A0x;
      cvt.u[1] = up ? B0y : A0y;
      cvt.u[2] = up ? B1x : A1x;
      cvt.u[3] = up ? B1y : A1y;
      pf[c2] = cvt.v;
    }

    // ---- O^T += V^T * P^T ----
#pragma unroll
    for (int dt = 0; dt < 4; ++dt) {
      const int rb = (dt * 16 + lo) * 128;
#pragma unroll
      for (int c2 = 0; c2 < 2; ++c2) {
        bf16x8 vf = *reinterpret_cast<const bf16x8*>(smV + rb + ((c2 * 64 + hi4 * 16) ^ swzA));
        o[dt] = MFMA16(vf, pf[c2], o[dt], 0, 0, 0);
      }
    }
  }

  // ---- normalize + store (O^T: lane has q=lo, d = dt*16 + hi4*4 + reg) ----
  const float inv = 1.0f / l_run;
  float* op = Og + ((size_t)((b * Lc + qrow) * Hc + h)) * Dc;
#pragma unroll
  for (int dt = 0; dt < 4; ++dt) {
    float4 st;
    st.x = o[dt][0] * inv; st.y = o[dt][1] * inv;
    st.z = o[dt][2] * inv; st.w = o[dt][3] * inv;
    *reinterpret_cast<float4*>(op + dt * 16 + hi4 * 4) = st;
  }
}

extern "C" void kernel_launch(void* const* d_in, const int* in_sizes, int n_in,
                              void* d_out, int out_size, void* d_ws, size_t ws_size,
                              hipStream_t stream) {
  const float* Qg = (const float*)d_in[0];
  const float* Kg = (const float*)d_in[1];
  const float* Vg = (const float*)d_in[2];
  float* Og = (float*)d_out;
  dim3 grid(Bc * Hc * (Lc / 64));   // 2048 blocks: (b,h) major, q-tile minor
  dim3 block(256);
  hipLaunchKernelGGL(fattn_kernel, grid, block, 0, stream, Qg, Kg, Vg, Og);
}

// Round 2
// 128.966 us; speedup vs baseline: 1.7195x; 1.7195x over previous
//
#include <hip/hip_runtime.h>

typedef __attribute__((ext_vector_type(8))) short bf16x8;
typedef __attribute__((ext_vector_type(8))) unsigned short u16x8;
typedef __attribute__((ext_vector_type(4))) float f32x4;

#define MFMA16 __builtin_amdgcn_mfma_f32_16x16x32_bf16

constexpr int Bc = 4, Lc = 2048, Hc = 16, Dc = 64;
// (1/sqrt(64)) * log2(e)
constexpr float SCL = 0.18033688011112042f;

__device__ __forceinline__ unsigned short f2bf(float f) {
  unsigned u = __float_as_uint(f);
  u += 0x7fff + ((u >> 16) & 1);   // RNE
  return (unsigned short)(u >> 16);
}

__device__ __forceinline__ float fexp2(float x) {
  return __builtin_amdgcn_exp2f(x);
}

__device__ __forceinline__ void glds16(const char* g, char* l) {
  __builtin_amdgcn_global_load_lds(
      (const __attribute__((address_space(1))) unsigned*)g,
      (__attribute__((address_space(3))) unsigned*)l, 16, 0, 0);
}

// ---------------------------------------------------------------------------
// Pre-pass: build bf16 blobs in workspace.
//   KB blob (head,tile): [64 k][128 B] rows, byte (2d)^((k&7)<<4) = K[k][d]
//   VB blob (head,tile): [64 d][128 B] rows, byte (2k)^((d&7)<<4) = V[k][d]
// These are exact LDS images: attention stages them with linear
// global_load_lds and reads with the XOR-swizzled ds_read pattern.
// ---------------------------------------------------------------------------
__global__ __launch_bounds__(256)
void prep_kernel(const float* __restrict__ Kg, const float* __restrict__ Vg,
                 char* __restrict__ KB, char* __restrict__ VB) {
  __shared__ __align__(16) short vt[64 * 72];

  const int bid = blockIdx.x;
  const int bh = bid >> 5;         // 0..63
  const int t  = bid & 31;         // kv-tile
  const int b  = bh >> 4;
  const int h  = bh & 15;

  const int tid = threadIdx.x;
  const int r   = tid >> 2;        // row 0..63
  const int seg = (tid & 3) * 16;  // 16-col segment

  const size_t srow = ((size_t)((b * Lc + t * 64 + r) * Hc + h)) * Dc + seg;

  // ---- K: convert + swizzled blob write ----
  {
    const float* kp = Kg + srow;
    float4 c0 = *reinterpret_cast<const float4*>(kp + 0);
    float4 c1 = *reinterpret_cast<const float4*>(kp + 4);
    float4 c2 = *reinterpret_cast<const float4*>(kp + 8);
    float4 c3 = *reinterpret_cast<const float4*>(kp + 12);
    u16x8 w0, w1;
    w0[0] = f2bf(c0.x); w0[1] = f2bf(c0.y); w0[2] = f2bf(c0.z); w0[3] = f2bf(c0.w);
    w0[4] = f2bf(c1.x); w0[5] = f2bf(c1.y); w0[6] = f2bf(c1.z); w0[7] = f2bf(c1.w);
    w1[0] = f2bf(c2.x); w1[1] = f2bf(c2.y); w1[2] = f2bf(c2.z); w1[3] = f2bf(c2.w);
    w1[4] = f2bf(c3.x); w1[5] = f2bf(c3.y); w1[6] = f2bf(c3.z); w1[7] = f2bf(c3.w);
    char* dst = KB + ((size_t)(bh * 32 + t)) * 8192 + r * 128;
    const int swz = (r & 7) << 4;
    *reinterpret_cast<u16x8*>(dst + ((seg * 2) ^ swz)) = w0;
    *reinterpret_cast<u16x8*>(dst + ((seg * 2 + 16) ^ swz)) = w1;
  }

  // ---- V: convert + LDS transpose ----
  {
    const float* vp = Vg + srow;
    float4 v0 = *reinterpret_cast<const float4*>(vp + 0);
    float4 v1 = *reinterpret_cast<const float4*>(vp + 4);
    float4 v2 = *reinterpret_cast<const float4*>(vp + 8);
    float4 v3 = *reinterpret_cast<const float4*>(vp + 12);
    float vv[16];
    vv[0] = v0.x; vv[1] = v0.y; vv[2] = v0.z; vv[3] = v0.w;
    vv[4] = v1.x; vv[5] = v1.y; vv[6] = v1.z; vv[7] = v1.w;
    vv[8] = v2.x; vv[9] = v2.y; vv[10] = v2.z; vv[11] = v2.w;
    vv[12] = v3.x; vv[13] = v3.y; vv[14] = v3.z; vv[15] = v3.w;
#pragma unroll
    for (int j = 0; j < 16; ++j)
      vt[(seg + j) * 72 + r] = (short)f2bf(vv[j]);
  }
  __syncthreads();

  // ---- V^T rows → swizzled blob write ----
  {
    const int d  = tid >> 2;
    const int sk = (tid & 3) * 16;
    u16x8 a0 = *reinterpret_cast<const u16x8*>(vt + d * 72 + sk);
    u16x8 a1 = *reinterpret_cast<const u16x8*>(vt + d * 72 + sk + 8);
    char* dst = VB + ((size_t)(bh * 32 + t)) * 8192 + d * 128;
    const int swz = (d & 7) << 4;
    *reinterpret_cast<u16x8*>(dst + ((sk * 2) ^ swz)) = a0;
    *reinterpret_cast<u16x8*>(dst + ((sk * 2 + 16) ^ swz)) = a1;
  }
}

// ---------------------------------------------------------------------------
// Flash attention: 1 block = 64 q-rows of one head; double-buffered DMA
// staging from pre-swizzled blobs; counted vmcnt on the ready barrier.
// ---------------------------------------------------------------------------
__global__ __launch_bounds__(256)
void fattn2_kernel(const float* __restrict__ Qg, const char* __restrict__ KB,
                   const char* __restrict__ VB, float* __restrict__ Og) {
  __shared__ __align__(128) char smem[32768];   // 2 bufs x (K 8K + V 8K)

  // XCD swizzle: 2048 blocks, 8 XCDs -> each XCD owns 8 full heads.
  const int p    = blockIdx.x;
  const int wk   = (p & 7) * 256 + (p >> 3);
  const int head = wk >> 5;
  const int qt   = wk & 31;
  const int b    = head >> 4;
  const int h    = head & 15;
  const int q0   = qt * 64;

  const int tid = threadIdx.x;
  const int w   = tid >> 6;
  const int l   = tid & 63;
  const int lo  = l & 15;
  const int hi4 = l >> 4;
  const int swzA = (lo & 7) << 4;

  // ---- Q fragments (B-operand of S^T = K * Q^T) ----
  const int qrow = q0 + w * 16 + lo;
  const float* qp = Qg + ((size_t)((b * Lc + qrow) * Hc + h)) * Dc;
  bf16x8 qf[2];
#pragma unroll
  for (int dc = 0; dc < 2; ++dc) {
    float4 a = *reinterpret_cast<const float4*>(qp + dc * 32 + hi4 * 8);
    float4 c = *reinterpret_cast<const float4*>(qp + dc * 32 + hi4 * 8 + 4);
    bf16x8 f;
    f[0] = (short)f2bf(a.x); f[1] = (short)f2bf(a.y);
    f[2] = (short)f2bf(a.z); f[3] = (short)f2bf(a.w);
    f[4] = (short)f2bf(c.x); f[5] = (short)f2bf(c.y);
    f[6] = (short)f2bf(c.z); f[7] = (short)f2bf(c.w);
    qf[dc] = f;
  }

  f32x4 o[4];
#pragma unroll
  for (int dt = 0; dt < 4; ++dt) { o[dt][0] = 0.f; o[dt][1] = 0.f; o[dt][2] = 0.f; o[dt][3] = 0.f; }
  float m_run = -3.0e38f, l_run = 0.0f;

  const char* kbase = KB + ((size_t)head * 32) * 8192;
  const char* vbase = VB + ((size_t)head * 32) * 8192;
  const int wo = w * 1024 + l * 16;
  const int wl = w * 1024;

  auto stage = [&](int bufi, int kt) {
    const char* kb = kbase + (size_t)kt * 8192;
    const char* vb = vbase + (size_t)kt * 8192;
    char* dK = smem + bufi * 16384;
    char* dV = dK + 8192;
    glds16(kb + wo, dK + wl);
    glds16(kb + 4096 + wo, dK + 4096 + wl);
    glds16(vb + wo, dV + wl);
    glds16(vb + 4096 + wo, dV + 4096 + wl);
  };

  const int nkt = qt + 1;
  int buf = 0;
  stage(0, 0);

  for (int kt = 0; kt < nkt; ++kt) {
    if (kt + 1 < nkt) {
      stage(buf ^ 1, kt + 1);
      asm volatile("s_waitcnt vmcnt(4)" ::: "memory");  // current tile ready
    } else {
      asm volatile("s_waitcnt vmcnt(0)" ::: "memory");
    }
    __builtin_amdgcn_s_barrier();   // ready barrier (prefetch stays in flight)

    const char* smK = smem + buf * 16384;
    const char* smV = smK + 8192;
    const int kv0 = kt * 64;

    // ---- S^T = K * Q^T ----
    f32x4 s[4];
#pragma unroll
    for (int ks = 0; ks < 4; ++ks) {
      const int rb = (ks * 16 + lo) * 128;
      bf16x8 a0 = *reinterpret_cast<const bf16x8*>(smK + rb + ((hi4 * 16) ^ swzA));
      bf16x8 a1 = *reinterpret_cast<const bf16x8*>(smK + rb + ((64 + hi4 * 16) ^ swzA));
      f32x4 c; c[0] = 0.f; c[1] = 0.f; c[2] = 0.f; c[3] = 0.f;
      c = MFMA16(a0, qf[0], c, 0, 0, 0);
      c = MFMA16(a1, qf[1], c, 0, 0, 0);
      s[ks] = c;
    }

    // ---- scale + causal mask + online softmax ----
    const bool diag = (kt == nkt - 1);
    float vmax = -3.0e38f;
#pragma unroll
    for (int ks = 0; ks < 4; ++ks) {
#pragma unroll
      for (int i = 0; i < 4; ++i) {
        float x = s[ks][i] * SCL;
        if (diag) {
          const int kg = kv0 + ks * 16 + hi4 * 4 + i;
          if (kg > qrow) x = -3.0e38f;
        }
        s[ks][i] = x;
        vmax = fmaxf(vmax, x);
      }
    }
    vmax = fmaxf(vmax, __shfl_xor(vmax, 16));
    vmax = fmaxf(vmax, __shfl_xor(vmax, 32));
    const float m_new = fmaxf(m_run, vmax);
    const float alpha = fexp2(m_run - m_new);

    float rsum = 0.f;
    unsigned pk2[4][2];
#pragma unroll
    for (int ks = 0; ks < 4; ++ks) {
      const float p0 = fexp2(s[ks][0] - m_new);
      const float p1 = fexp2(s[ks][1] - m_new);
      const float p2 = fexp2(s[ks][2] - m_new);
      const float p3 = fexp2(s[ks][3] - m_new);
      rsum += (p0 + p1) + (p2 + p3);
      pk2[ks][0] = (unsigned)f2bf(p0) | ((unsigned)f2bf(p1) << 16);
      pk2[ks][1] = (unsigned)f2bf(p2) | ((unsigned)f2bf(p3) << 16);
    }
    rsum += __shfl_xor(rsum, 16);
    rsum += __shfl_xor(rsum, 32);
    l_run = l_run * alpha + rsum;
    m_run = m_new;
#pragma unroll
    for (int dt = 0; dt < 4; ++dt) {
      o[dt][0] *= alpha; o[dt][1] *= alpha; o[dt][2] *= alpha; o[dt][3] *= alpha;
    }

    // ---- rearrange P^T (C-layout) into K=32 B-fragments via shfl ----
    const int srcA = lo + ((l & 16) << 1);
    const int srcB = srcA + 16;
    const bool up = (l & 32) != 0;
    bf16x8 pf[2];
#pragma unroll
    for (int c2 = 0; c2 < 2; ++c2) {
      const unsigned A0x = (unsigned)__shfl((int)pk2[2 * c2][0], srcA);
      const unsigned A0y = (unsigned)__shfl((int)pk2[2 * c2][1], srcA);
      const unsigned A1x = (unsigned)__shfl((int)pk2[2 * c2][0], srcB);
      const unsigned A1y = (unsigned)__shfl((int)pk2[2 * c2][1], srcB);
      const unsigned B0x = (unsigned)__shfl((int)pk2[2 * c2 + 1][0], srcA);
      const unsigned B0y = (unsigned)__shfl((int)pk2[2 * c2 + 1][1], srcA);
      const unsigned B1x = (unsigned)__shfl((int)pk2[2 * c2 + 1][0], srcB);
      const unsigned B1y = (unsigned)__shfl((int)pk2[2 * c2 + 1][1], srcB);
      union { unsigned u[4]; bf16x8 v; } cvt;
      cvt.u[0] = up ? B0x : A0x;
      cvt.u[1] = up ? B0y : A0y;
      cvt.u[2] = up ? B1x : A1x;
      cvt.u[3] = up ? B1y : A1y;
      pf[c2] = cvt.v;
    }

    // ---- O^T += V^T * P^T ----
#pragma unroll
    for (int dt = 0; dt < 4; ++dt) {
      const int rb = (dt * 16 + lo) * 128;
#pragma unroll
      for (int c2 = 0; c2 < 2; ++c2) {
        bf16x8 vf = *reinterpret_cast<const bf16x8*>(smV + rb + ((c2 * 64 + hi4 * 16) ^ swzA));
        o[dt] = MFMA16(vf, pf[c2], o[dt], 0, 0, 0);
      }
    }

    __syncthreads();   // overwrite barrier (vmcnt(0) here lands after compute)
    buf ^= 1;
  }

  // ---- normalize + store ----
  const float inv = 1.0f / l_run;
  float* op = Og + ((size_t)((b * Lc + qrow) * Hc + h)) * Dc;
#pragma unroll
  for (int dt = 0; dt < 4; ++dt) {
    float4 st;
    st.x = o[dt][0] * inv; st.y = o[dt][1] * inv;
    st.z = o[dt][2] * inv; st.w = o[dt][3] * inv;
    *reinterpret_cast<float4*>(op + dt * 16 + hi4 * 4) = st;
  }
}

// ---------------------------------------------------------------------------
// Round-1 fallback (used only if ws_size is too small for the blobs).
// ---------------------------------------------------------------------------
__global__ __launch_bounds__(256)
void fattn_fallback(const float* __restrict__ Qg, const float* __restrict__ Kg,
                    const float* __restrict__ Vg, float* __restrict__ Og) {
  __shared__ __align__(128) char smem[32768];
  char* smK = smem;
  char* smV = smem + 16384;

  const int bid  = blockIdx.x;
  const int head = bid >> 5;
  const int qt   = bid & 31;
  const int b    = head >> 4;
  const int h    = head & 15;
  const int q0   = qt * 64;

  const int tid = threadIdx.x;
  const int w   = tid >> 6;
  const int l   = tid & 63;
  const int lo  = l & 15;
  const int hi4 = l >> 4;

  const int qrow = q0 + w * 16 + lo;
  const float* qp = Qg + ((size_t)((b * Lc + qrow) * Hc + h)) * Dc;
  bf16x8 qf[2];
#pragma unroll
  for (int dc = 0; dc < 2; ++dc) {
    float4 a = *reinterpret_cast<const float4*>(qp + dc * 32 + hi4 * 8);
    float4 c = *reinterpret_cast<const float4*>(qp + dc * 32 + hi4 * 8 + 4);
    bf16x8 f;
    f[0] = (short)f2bf(a.x); f[1] = (short)f2bf(a.y);
    f[2] = (short)f2bf(a.z); f[3] = (short)f2bf(a.w);
    f[4] = (short)f2bf(c.x); f[5] = (short)f2bf(c.y);
    f[6] = (short)f2bf(c.z); f[7] = (short)f2bf(c.w);
    qf[dc] = f;
  }

  f32x4 o[4];
#pragma unroll
  for (int dt = 0; dt < 4; ++dt) { o[dt][0] = 0.f; o[dt][1] = 0.f; o[dt][2] = 0.f; o[dt][3] = 0.f; }
  float m_run = -3.0e38f, l_run = 0.0f;

  const int sk   = tid >> 2;
  const int sd   = (tid & 3) * 16;
  const int swzK = (sk & 7) << 4;
  const int swzA = (lo & 7) << 4;

  const int nkt = qt + 1;
  for (int kt = 0; kt < nkt; ++kt) {
    const int kv0 = kt * 64;
    __syncthreads();
    {
      const float* kpr = Kg + ((size_t)((b * Lc + kv0 + sk) * Hc + h)) * Dc + sd;
      float4 c0 = *reinterpret_cast<const float4*>(kpr + 0);
      float4 c1 = *reinterpret_cast<const float4*>(kpr + 4);
      float4 c2 = *reinterpret_cast<const float4*>(kpr + 8);
      float4 c3 = *reinterpret_cast<const float4*>(kpr + 12);
      u16x8 w0, w1;
      w0[0] = f2bf(c0.x); w0[1] = f2bf(c0.y); w0[2] = f2bf(c0.z); w0[3] = f2bf(c0.w);
      w0[4] = f2bf(c1.x); w0[5] = f2bf(c1.y); w0[6] = f2bf(c1.z); w0[7] = f2bf(c1.w);
      w1[0] = f2bf(c2.x); w1[1] = f2bf(c2.y); w1[2] = f2bf(c2.z); w1[3] = f2bf(c2.w);
      w1[4] = f2bf(c3.x); w1[5] = f2bf(c3.y); w1[6] = f2bf(c3.z); w1[7] = f2bf(c3.w);
      *reinterpret_cast<u16x8*>(smK + sk * 128 + ((sd * 2) ^ swzK)) = w0;
      *reinterpret_cast<u16x8*>(smK + sk * 128 + ((sd * 2 + 16) ^ swzK)) = w1;

      const float* vpr = Vg + ((size_t)((b * Lc + kv0 + sk) * Hc + h)) * Dc + sd;
      float4 v0 = *reinterpret_cast<const float4*>(vpr + 0);
      float4 v1 = *reinterpret_cast<const float4*>(vpr + 4);
      float4 v2 = *reinterpret_cast<const float4*>(vpr + 8);
      float4 v3 = *reinterpret_cast<const float4*>(vpr + 12);
      float vv[16];
      vv[0] = v0.x; vv[1] = v0.y; vv[2] = v0.z; vv[3] = v0.w;
      vv[4] = v1.x; vv[5] = v1.y; vv[6] = v1.z; vv[7] = v1.w;
      vv[8] = v2.x; vv[9] = v2.y; vv[10] = v2.z; vv[11] = v2.w;
      vv[12] = v3.x; vv[13] = v3.y; vv[14] = v3.z; vv[15] = v3.w;
#pragma unroll
      for (int j = 0; j < 16; ++j) {
        const int d = sd + j;
        *reinterpret_cast<unsigned short*>(smV + d * 128 + ((sk * 2) ^ ((j & 7) << 4))) = f2bf(vv[j]);
      }
    }
    __syncthreads();

    f32x4 s[4];
#pragma unroll
    for (int ks = 0; ks < 4; ++ks) {
      const int rb = (ks * 16 + lo) * 128;
      bf16x8 a0 = *reinterpret_cast<const bf16x8*>(smK + rb + ((hi4 * 16) ^ swzA));
      bf16x8 a1 = *reinterpret_cast<const bf16x8*>(smK + rb + ((64 + hi4 * 16) ^ swzA));
      f32x4 c; c[0] = 0.f; c[1] = 0.f; c[2] = 0.f; c[3] = 0.f;
      c = MFMA16(a0, qf[0], c, 0, 0, 0);
      c = MFMA16(a1, qf[1], c, 0, 0, 0);
      s[ks] = c;
    }

    const bool diag = (kt == nkt - 1);
    float vmax = -3.0e38f;
#pragma unroll
    for (int ks = 0; ks < 4; ++ks) {
#pragma unroll
      for (int i = 0; i < 4; ++i) {
        float x = s[ks][i] * SCL;
        if (diag) {
          const int kg = kv0 + ks * 16 + hi4 * 4 + i;
          if (kg > qrow) x = -3.0e38f;
        }
        s[ks][i] = x;
        vmax = fmaxf(vmax, x);
      }
    }
    vmax = fmaxf(vmax, __shfl_xor(vmax, 16));
    vmax = fmaxf(vmax, __shfl_xor(vmax, 32));
    const float m_new = fmaxf(m_run, vmax);
    const float alpha = fexp2(m_run - m_new);

    float rsum = 0.f;
    unsigned pk2[4][2];
#pragma unroll
    for (int ks = 0; ks < 4; ++ks) {
      const float p0 = fexp2(s[ks][0] - m_new);
      const float p1 = fexp2(s[ks][1] - m_new);
      const float p2 = fexp2(s[ks][2] - m_new);
      const float p3 = fexp2(s[ks][3] - m_new);
      rsum += (p0 + p1) + (p2 + p3);
      pk2[ks][0] = (unsigned)f2bf(p0) | ((unsigned)f2bf(p1) << 16);
      pk2[ks][1] = (unsigned)f2bf(p2) | ((unsigned)f2bf(p3) << 16);
    }
    rsum += __shfl_xor(rsum, 16);
    rsum += __shfl_xor(rsum, 32);
    l_run = l_run * alpha + rsum;
    m_run = m_new;
#pragma unroll
    for (int dt = 0; dt < 4; ++dt) {
      o[dt][0] *= alpha; o[dt][1] *= alpha; o[dt][2] *= alpha; o[dt][3] *= alpha;
    }

    const int srcA = lo + ((l & 16) << 1);
    const int srcB = srcA + 16;
    const bool up = (l & 32) != 0;
    bf16x8 pf[2];
#pragma unroll
    for (int c2 = 0; c2 < 2; ++c2) {
      const unsigned A0x = (unsigned)__shfl((int)pk2[2 * c2][0], srcA);
      const unsigned A0y = (unsigned)__shfl((int)pk2[2 * c2][1], srcA);
      const unsigned A1x = (unsigned)__shfl((int)pk2[2 * c2][0], srcB);
      const unsigned A1y = (unsigned)__shfl((int)pk2[2 * c2][1], srcB);
      const unsigned B0x = (unsigned)__shfl((int)pk2[2 * c2 + 1][0], srcA);
      const unsigned B0y = (unsigned)__shfl((int)pk2[2 * c2 + 1][1], srcA);
      const unsigned B1x = (unsigned)__shfl((int)pk2[2 * c2 + 1][0], srcB);
      const unsigned B1y = (unsigned)__shfl((int)pk2[2 * c2 + 1][1], srcB);
      union { unsigned u[4]; bf16x8 v; } cvt;
      cvt.u[0] = up ? B0x : A0x;
      cvt.u[1] = up ? B0y : A0y;
      cvt.u[2] = up ? B1x : A1x;
      cvt.u[3] = up ? B1y : A1y;
      pf[c2] = cvt.v;
    }

#pragma unroll
    for (int dt = 0; dt < 4; ++dt) {
      const int rb = (dt * 16 + lo) * 128;
#pragma unroll
      for (int c2 = 0; c2 < 2; ++c2) {
        bf16x8 vf = *reinterpret_cast<const bf16x8*>(smV + rb + ((c2 * 64 + hi4 * 16) ^ swzA));
        o[dt] = MFMA16(vf, pf[c2], o[dt], 0, 0, 0);
      }
    }
  }

  const float inv = 1.0f / l_run;
  float* op = Og + ((size_t)((b * Lc + qrow) * Hc + h)) * Dc;
#pragma unroll
  for (int dt = 0; dt < 4; ++dt) {
    float4 st;
    st.x = o[dt][0] * inv; st.y = o[dt][1] * inv;
    st.z = o[dt][2] * inv; st.w = o[dt][3] * inv;
    *reinterpret_cast<float4*>(op + dt * 16 + hi4 * 4) = st;
  }
}

extern "C" void kernel_launch(void* const* d_in, const int* in_sizes, int n_in,
                              void* d_out, int out_size, void* d_ws, size_t ws_size,
                              hipStream_t stream) {
  const float* Qg = (const float*)d_in[0];
  const float* Kg = (const float*)d_in[1];
  const float* Vg = (const float*)d_in[2];
  float* Og = (float*)d_out;

  const size_t blob_bytes = (size_t)64 * 32 * 8192;   // 16.78 MB per tensor
  if (ws_size >= 2 * blob_bytes) {
    char* KB = (char*)d_ws;
    char* VB = KB + blob_bytes;
    hipLaunchKernelGGL(prep_kernel, dim3(2048), dim3(256), 0, stream, Kg, Vg, KB, VB);
    hipLaunchKernelGGL(fattn2_kernel, dim3(2048), dim3(256), 0, stream, Qg, KB, VB, Og);
  } else {
    hipLaunchKernelGGL(fattn_fallback, dim3(2048), dim3(256), 0, stream, Qg, Kg, Vg, Og);
  }
}